// Round 1
// baseline (232.053 us; speedup 1.0000x reference)
//
#include <hip/hip_runtime.h>
#include <hip/hip_bf16.h>
#include <cstdint>

#define NPIX 16384   // h*w = 128*128
#define BATCH 8
#define CDIM 256
#define MQKV 768

typedef __bf16 bh8 __attribute__((ext_vector_type(8)));
typedef __bf16 bh4 __attribute__((ext_vector_type(4)));
typedef float  fx4 __attribute__((ext_vector_type(4)));

__device__ __forceinline__ void gload16(const void* g, void* l) {
  __builtin_amdgcn_global_load_lds(
      (const __attribute__((address_space(1))) uint32_t*)g,
      (__attribute__((address_space(3))) uint32_t*)l, 16, 0, 0);
}

__device__ __forceinline__ fx4 mfma16(bh8 a, bh8 b, fx4 c) {
  return __builtin_amdgcn_mfma_f32_16x16x32_bf16(a, b, c, 0, 0, 0);
}

// ---------------- pass 0a: convert w_qkv f32 -> bf16 (row-major [768][256]) --
__global__ void conv_w(const float* __restrict__ w, __bf16* __restrict__ wb, int n) {
  int i = blockIdx.x * 256 + threadIdx.x;
  if (i < n) wb[i] = (__bf16)w[i];
}

// ---------------- pass 0b: x [b][256][NPIX] f32 -> xT [b][NPIX][256] bf16 ----
__global__ __launch_bounds__(256) void transpose_x(const float* __restrict__ x,
                                                   __bf16* __restrict__ xT) {
  __shared__ float tile[32][33];
  const int n0 = blockIdx.x * 32, c0 = blockIdx.y * 32, b = blockIdx.z;
  const int tx = threadIdx.x & 31, ty = threadIdx.x >> 5;
#pragma unroll
  for (int j = 0; j < 4; ++j) {
    int r = ty * 4 + j;  // local c
    tile[r][tx] = x[((size_t)b * CDIM + c0 + r) * NPIX + n0 + tx];
  }
  __syncthreads();
#pragma unroll
  for (int j = 0; j < 4; ++j) {
    int nl = ty * 4 + j; // local n
    xT[((size_t)b * NPIX + n0 + nl) * CDIM + c0 + tx] = (__bf16)tile[tx][nl];
  }
}

// ---------------- pass 1: qkv GEMM.  A=Wqkv[768][256], B^T=xT[n][256] --------
// writes qT (transposed bf16), k & v (row-major bf16, scratch in d_out)
__global__ __launch_bounds__(256) void gemm_qkv(const __bf16* __restrict__ Wq,
                                                const __bf16* __restrict__ xT,
                                                __bf16* __restrict__ qT,
                                                __bf16* __restrict__ kmat,
                                                __bf16* __restrict__ vmat) {
  __shared__ __bf16 As[128 * 32];
  __shared__ __bf16 Bs[128 * 32];
  const int bx = blockIdx.x, by = blockIdx.y, b = blockIdx.z;
  const int t = threadIdx.x;
  const int wid = t >> 6, lane = t & 63, fr = lane & 15, fq = lane >> 4;
  const int wm = wid >> 1, wn = wid & 1;
  const __bf16* Bbase = xT + (size_t)b * NPIX * CDIM;

  fx4 acc[4][4] = {};
  for (int kt = 0; kt < 8; ++kt) {
    const int k0 = kt * 32;
#pragma unroll
    for (int i = 0; i < 2; ++i) {           // stage A (128x32)
      int e0 = i * 2048 + t * 8;
      int row = e0 >> 5, col = e0 & 31;
      gload16(Wq + (size_t)(by * 128 + row) * CDIM + k0 + col, (void*)(As + e0));
    }
#pragma unroll
    for (int i = 0; i < 2; ++i) {           // stage B (128x32)
      int e0 = i * 2048 + t * 8;
      int row = e0 >> 5, col = e0 & 31;
      gload16(Bbase + (size_t)(bx * 128 + row) * CDIM + k0 + col, (void*)(Bs + e0));
    }
    __syncthreads();
    bh8 a[4], bb[4];
#pragma unroll
    for (int m = 0; m < 4; ++m)
      a[m] = *(const bh8*)&As[(wm * 64 + m * 16 + fr) * 32 + fq * 8];
#pragma unroll
    for (int n = 0; n < 4; ++n)
      bb[n] = *(const bh8*)&Bs[(wn * 64 + n * 16 + fr) * 32 + fq * 8];
#pragma unroll
    for (int m = 0; m < 4; ++m)
#pragma unroll
      for (int n = 0; n < 4; ++n) acc[m][n] = mfma16(a[m], bb[n], acc[m][n]);
    __syncthreads();
  }

  const int mat = by >> 1;  // 0=q, 1=k, 2=v (BM=128, 256-row aligned groups)
#pragma unroll
  for (int m = 0; m < 4; ++m) {
#pragma unroll
    for (int n = 0; n < 4; ++n) {
      int r0 = by * 128 + wm * 64 + m * 16 + fq * 4;  // global o row
      int o = r0 & 255;
      int cc = bx * 128 + wn * 64 + n * 16 + fr;      // pixel n
      if (mat == 0) {
        bh4 v4;
#pragma unroll
        for (int j = 0; j < 4; ++j) v4[j] = (__bf16)acc[m][n][j];
        *(bh4*)&qT[((size_t)b * NPIX + cc) * CDIM + o] = v4;
      } else {
        __bf16* dst = (mat == 1) ? kmat : vmat;
#pragma unroll
        for (int j = 0; j < 4; ++j)
          dst[((size_t)b * CDIM + o + j) * NPIX + cc] = (__bf16)acc[m][n][j];
      }
    }
  }
}

// ---------------- pass 2: S[d][e] = sum_n exp(k[d,n]) v[e,n]; Z[d]=sum exp ---
// per block: (b, h, 256-wide n-chunk). MFMA 32x32 with split-K partials.
__global__ __launch_bounds__(256) void ctx_kernel(const __bf16* __restrict__ kmat,
                                                  const __bf16* __restrict__ vmat,
                                                  float* __restrict__ S_part,
                                                  float* __restrict__ Zsum) {
  const int chunk = blockIdx.x, h = blockIdx.y, b = blockIdx.z;
  const int t = threadIdx.x;
  const int n0 = chunk * 256;
  __shared__ __bf16 EK[32 * 256];
  __shared__ __bf16 VS[32 * 256];
  __shared__ float zrow[32];

  if (t < 32) zrow[t] = 0.f;
  __syncthreads();

  {  // stage exp(k): thread -> row t>>3, 32 cols
    const int row = t >> 3, c0 = (t & 7) * 32;
    const __bf16* src = kmat + ((size_t)b * CDIM + h * 32 + row) * NPIX + n0 + c0;
    float zacc = 0.f;
#pragma unroll
    for (int i = 0; i < 4; ++i) {
      bh8 raw = *(const bh8*)(src + i * 8);
      bh8 ev;
#pragma unroll
      for (int j = 0; j < 8; ++j) {
        float e = __expf((float)raw[j]);
        zacc += e;
        ev[j] = (__bf16)e;
      }
      *(bh8*)&EK[row * 256 + c0 + i * 8] = ev;
    }
    atomicAdd(&zrow[row], zacc);
  }
  {  // stage v straight via global_load_lds
#pragma unroll
    for (int i = 0; i < 4; ++i) {
      int e0 = i * 2048 + t * 8;
      int row = e0 >> 8, col = e0 & 255;
      gload16(vmat + ((size_t)b * CDIM + h * 32 + row) * NPIX + n0 + col,
              (void*)(VS + e0));
    }
  }
  __syncthreads();

  const int wid = t >> 6, lane = t & 63, fr = lane & 15, fq = lane >> 4;
  fx4 acc[2][2] = {};
  const int kbase = wid * 64;  // each wave: 64 of the 256 K
#pragma unroll
  for (int kk = 0; kk < 2; ++kk) {
    bh8 a[2], bb[2];
#pragma unroll
    for (int m = 0; m < 2; ++m)
      a[m] = *(const bh8*)&EK[(m * 16 + fr) * 256 + kbase + kk * 32 + fq * 8];
#pragma unroll
    for (int n = 0; n < 2; ++n)
      bb[n] = *(const bh8*)&VS[(n * 16 + fr) * 256 + kbase + kk * 32 + fq * 8];
#pragma unroll
    for (int m = 0; m < 2; ++m)
#pragma unroll
      for (int n = 0; n < 2; ++n) acc[m][n] = mfma16(a[m], bb[n], acc[m][n]);
  }
  __syncthreads();
  float* red = (float*)EK;  // 4096 f32 scratch over EK (16 KB)
#pragma unroll
  for (int m = 0; m < 2; ++m)
#pragma unroll
    for (int n = 0; n < 2; ++n)
#pragma unroll
      for (int j = 0; j < 4; ++j)
        red[wid * 1024 + (m * 16 + fq * 4 + j) * 32 + (n * 16 + fr)] = acc[m][n][j];
  __syncthreads();
  const size_t bh = (size_t)b * 8 + h;
  for (int i = t; i < 1024; i += 256) {
    float s = red[i] + red[1024 + i] + red[2048 + i] + red[3072 + i];
    S_part[(bh * 64 + chunk) * 1024 + i] = s;
  }
  if (t < 32) atomicAdd(&Zsum[bh * 32 + t], zrow[t]);
}

// ---------------- pass 2.5: reduce S_part over chunks, divide by Z -> ctx ----
__global__ __launch_bounds__(256) void reduce_ctx(const float* __restrict__ S_part,
                                                  const float* __restrict__ Zsum,
                                                  float* __restrict__ ctx) {
  const int bh = blockIdx.x;  // 64
  const int t = threadIdx.x;
  for (int i = t; i < 1024; i += 256) {
    float s = 0.f;
    for (int ch = 0; ch < 64; ++ch) s += S_part[((size_t)bh * 64 + ch) * 1024 + i];
    ctx[(size_t)bh * 1024 + i] = s / Zsum[bh * 32 + (i >> 5)];
  }
}

// ---------------- pass 3: W2[b][oc][h*32+d] = sum_e w_out[oc][h*32+e]*ctx ----
__global__ __launch_bounds__(256) void make_w2(const float* __restrict__ ctx,
                                               const float* __restrict__ w_out,
                                               __bf16* __restrict__ W2) {
  const int oc = blockIdx.x, b = blockIdx.y, t = threadIdx.x;
  const int h = t >> 5, d = t & 31;
  const float* wrow = w_out + oc * 256 + h * 32;
  const float* crow = ctx + (((size_t)b * 8 + h) * 32 + d) * 32;
  float s = 0.f;
#pragma unroll
  for (int e = 0; e < 32; ++e) s += wrow[e] * crow[e];
  W2[((size_t)b * 256 + oc) * 256 + t] = (__bf16)s;
}

// ---------------- pass 4: out = W2[b] (256x256) * qT^T + b_out --------------
__global__ __launch_bounds__(256) void gemm_out(const __bf16* __restrict__ W2,
                                                const __bf16* __restrict__ qT,
                                                const float* __restrict__ b_out,
                                                float* __restrict__ out) {
  __shared__ __bf16 As[128 * 32];
  __shared__ __bf16 Bs[128 * 32];
  const int bx = blockIdx.x, by = blockIdx.y, b = blockIdx.z;
  const int t = threadIdx.x;
  const int wid = t >> 6, lane = t & 63, fr = lane & 15, fq = lane >> 4;
  const int wm = wid >> 1, wn = wid & 1;
  const __bf16* Abase = W2 + (size_t)b * 256 * 256;
  const __bf16* Bbase = qT + (size_t)b * NPIX * CDIM;

  fx4 acc[4][4] = {};
  for (int kt = 0; kt < 8; ++kt) {
    const int k0 = kt * 32;
#pragma unroll
    for (int i = 0; i < 2; ++i) {
      int e0 = i * 2048 + t * 8;
      int row = e0 >> 5, col = e0 & 31;
      gload16(Abase + (size_t)(by * 128 + row) * CDIM + k0 + col, (void*)(As + e0));
    }
#pragma unroll
    for (int i = 0; i < 2; ++i) {
      int e0 = i * 2048 + t * 8;
      int row = e0 >> 5, col = e0 & 31;
      gload16(Bbase + (size_t)(bx * 128 + row) * CDIM + k0 + col, (void*)(Bs + e0));
    }
    __syncthreads();
    bh8 a[4], bb[4];
#pragma unroll
    for (int m = 0; m < 4; ++m)
      a[m] = *(const bh8*)&As[(wm * 64 + m * 16 + fr) * 32 + fq * 8];
#pragma unroll
    for (int n = 0; n < 4; ++n)
      bb[n] = *(const bh8*)&Bs[(wn * 64 + n * 16 + fr) * 32 + fq * 8];
#pragma unroll
    for (int m = 0; m < 4; ++m)
#pragma unroll
      for (int n = 0; n < 4; ++n) acc[m][n] = mfma16(a[m], bb[n], acc[m][n]);
    __syncthreads();
  }

#pragma unroll
  for (int m = 0; m < 4; ++m) {
#pragma unroll
    for (int n = 0; n < 4; ++n) {
      int r0 = by * 128 + wm * 64 + m * 16 + fq * 4;  // out channel
      int cc = bx * 128 + wn * 64 + n * 16 + fr;      // pixel
#pragma unroll
      for (int j = 0; j < 4; ++j)
        out[((size_t)b * 256 + r0 + j) * NPIX + cc] = acc[m][n][j] + b_out[r0 + j];
    }
  }
}

extern "C" void kernel_launch(void* const* d_in, const int* in_sizes, int n_in,
                              void* d_out, int out_size, void* d_ws, size_t ws_size,
                              hipStream_t stream) {
  const float* x     = (const float*)d_in[0];
  const float* w_qkv = (const float*)d_in[1];
  const float* w_out = (const float*)d_in[2];
  const float* b_out = (const float*)d_in[3];
  float* out = (float*)d_out;

  char* ws = (char*)d_ws;
  // ws layout (bytes)
  __bf16* xT    = (__bf16*)(ws);                          // 67,108,864
  __bf16* qT    = (__bf16*)(ws + 67108864ull);            // 67,108,864
  __bf16* wqb   = (__bf16*)(ws + 134217728ull);           // 393,216
  __bf16* W2    = (__bf16*)(ws + 134610944ull);           // 1,048,576
  float*  S_part= (float*) (ws + 135659520ull);           // 16,777,216
  float*  Zsum  = (float*) (ws + 152436736ull);           // 8,192
  float*  ctx   = (float*) (ws + 152444928ull);           // 262,144  (end ~145.6 MiB)

  // k/v bf16 scratch lives inside d_out (fully overwritten by gemm_out later)
  __bf16* kmat = (__bf16*)d_out;                 // [8][256][NPIX] = 64 MiB
  __bf16* vmat = kmat + (size_t)BATCH * CDIM * NPIX;  // next 64 MiB

  hipMemsetAsync(Zsum, 0, 8192, stream);

  conv_w<<<768, 256, 0, stream>>>(w_qkv, wqb, MQKV * CDIM);
  transpose_x<<<dim3(NPIX / 32, CDIM / 32, BATCH), 256, 0, stream>>>(x, xT);
  gemm_qkv<<<dim3(NPIX / 128, MQKV / 128, BATCH), 256, 0, stream>>>(wqb, xT, qT, kmat, vmat);
  ctx_kernel<<<dim3(64, 8, BATCH), 256, 0, stream>>>(kmat, vmat, S_part, Zsum);
  reduce_ctx<<<64, 256, 0, stream>>>(S_part, Zsum, ctx);
  make_w2<<<dim3(256, BATCH), 256, 0, stream>>>(ctx, w_out, W2);
  gemm_out<<<dim3(NPIX / 128, 2, BATCH), 256, 0, stream>>>(W2, qT, b_out, out);
}

// Round 2
// 231.924 us; speedup vs baseline: 1.0006x; 1.0006x over previous
//
#include <hip/hip_runtime.h>
#include <hip/hip_bf16.h>
#include <cstdint>

#define NPIX 16384   // h*w = 128*128
#define BATCH 8
#define CDIM 256
#define MQKV 768

typedef __bf16 bh8 __attribute__((ext_vector_type(8)));
typedef __bf16 bh4 __attribute__((ext_vector_type(4)));
typedef float  fx4 __attribute__((ext_vector_type(4)));

__device__ __forceinline__ void gload16(const void* g, void* l) {
  __builtin_amdgcn_global_load_lds(
      (const __attribute__((address_space(1))) uint32_t*)g,
      (__attribute__((address_space(3))) uint32_t*)l, 16, 0, 0);
}

__device__ __forceinline__ fx4 mfma16(bh8 a, bh8 b, fx4 c) {
  return __builtin_amdgcn_mfma_f32_16x16x32_bf16(a, b, c, 0, 0, 0);
}

__device__ __forceinline__ void pbar() {
  asm volatile("" ::: "memory");
  __builtin_amdgcn_s_barrier();
  asm volatile("" ::: "memory");
}
#define VMW4() asm volatile("s_waitcnt vmcnt(4)" ::: "memory")
#define VMW0() asm volatile("s_waitcnt vmcnt(0)" ::: "memory")

// ---------------- pass 0a: convert w_qkv f32 -> bf16 (row-major [768][256]) --
__global__ void conv_w(const float* __restrict__ w, __bf16* __restrict__ wb, int n) {
  int i = blockIdx.x * 256 + threadIdx.x;
  if (i < n) wb[i] = (__bf16)w[i];
}

// ---------------- pass 0b: x [b][256][NPIX] f32 -> xT [b][NPIX][256] bf16 ----
__global__ __launch_bounds__(256) void transpose_x(const float* __restrict__ x,
                                                   __bf16* __restrict__ xT) {
  __shared__ float tile[32][33];
  const int n0 = blockIdx.x * 32, c0 = blockIdx.y * 32, b = blockIdx.z;
  const int tx = threadIdx.x & 31, ty = threadIdx.x >> 5;
#pragma unroll
  for (int j = 0; j < 4; ++j) {
    int r = ty * 4 + j;  // local c
    tile[r][tx] = x[((size_t)b * CDIM + c0 + r) * NPIX + n0 + tx];
  }
  __syncthreads();
#pragma unroll
  for (int j = 0; j < 4; ++j) {
    int nl = ty * 4 + j; // local n
    xT[((size_t)b * NPIX + n0 + nl) * CDIM + c0 + tx] = (__bf16)tile[tx][nl];
  }
}

// ================= 256x256 8-phase GEMM core, K=256 (4 tiles of BK=64) =======
// EPI==0: A=wqkv bf16 [768][256], by in {0,1,2} selects q/k/v; out1 gets exp()
// EPI==1: A=W2 [b][256][256], by==0; writes f32 out + bias
//
// 8 waves (2M x 4N), per-wave output 128x64. LDS 128 KiB, double-buffered.
// XOR swizzle: 16B chunk c at row r stored at chunk (c ^ (r&7)); staging
// pre-applies the inverse on the per-lane GLOBAL source (linear LDS dest).

#define MMA(mh, nh, bb)                                                        \
  do {                                                                         \
    __builtin_amdgcn_s_setprio(1);                                             \
    _Pragma("unroll") for (int m_ = 0; m_ < 4; ++m_)                           \
    _Pragma("unroll") for (int n_ = 0; n_ < 2; ++n_)                           \
    _Pragma("unroll") for (int k_ = 0; k_ < 2; ++k_)                           \
      acc[(mh)*4 + m_][(nh)*2 + n_] =                                          \
          mfma16(a[m_][k_], bb[n_][k_], acc[(mh)*4 + m_][(nh)*2 + n_]);        \
    __builtin_amdgcn_s_setprio(0);                                             \
  } while (0)

#define LDA(pbuf, mh)                                                          \
  do {                                                                         \
    _Pragma("unroll") for (int m_ = 0; m_ < 4; ++m_) {                         \
      int row_ = wm * 128 + (mh)*64 + m_ * 16 + fr;                            \
      a[m_][0] = *(const bh8*)&As[pbuf][row_ * 64 + sw0 * 8];                  \
      a[m_][1] = *(const bh8*)&As[pbuf][row_ * 64 + sw1 * 8];                  \
    }                                                                          \
  } while (0)

#define LDB(pbuf, nh, bb)                                                      \
  do {                                                                         \
    _Pragma("unroll") for (int n_ = 0; n_ < 2; ++n_) {                         \
      int row_ = wn * 64 + (nh)*32 + n_ * 16 + fr;                             \
      bb[n_][0] = *(const bh8*)&Bs[pbuf][row_ * 64 + sw0 * 8];                 \
      bb[n_][1] = *(const bh8*)&Bs[pbuf][row_ * 64 + sw1 * 8];                 \
    }                                                                          \
  } while (0)

// half: 0=A-lo 1=A-hi 2=B-lo 3=B-hi ; kt: K-tile index (64 cols each)
#define STG(pbuf, half, kt)                                                    \
  do {                                                                         \
    const __bf16* gb_;                                                         \
    __bf16* lb_;                                                               \
    if ((half) < 2) { gb_ = Ab + (size_t)((half)*128) * 256 + (kt)*64;         \
                      lb_ = &As[pbuf][(half)*8192]; }                          \
    else            { gb_ = Bb + (size_t)(((half)-2) * 128) * 256 + (kt)*64;   \
                      lb_ = &Bs[pbuf][((half)-2) * 8192]; }                    \
    _Pragma("unroll") for (int i_ = 0; i_ < 2; ++i_) {                         \
      int ci_ = i_ * 512 + tid;                                                \
      int row_ = ci_ >> 3, cc_ = ci_ & 7;                                      \
      int sc_ = cc_ ^ (row_ & 7);                                              \
      gload16(gb_ + (size_t)row_ * 256 + sc_ * 8, lb_ + ci_ * 8);              \
    }                                                                          \
  } while (0)

template <int EPI>
__global__ __launch_bounds__(512, 2) void gemm256(
    const __bf16* __restrict__ A, const __bf16* __restrict__ Bx,
    __bf16* __restrict__ qT, __bf16* __restrict__ ekmat,
    __bf16* __restrict__ vmat, const float* __restrict__ bias,
    float* __restrict__ fout) {
  __shared__ __bf16 As[2][16384];
  __shared__ __bf16 Bs[2][16384];
  const int tid = threadIdx.x;
  const int bx = blockIdx.x, by = blockIdx.y, b = blockIdx.z;
  const int lane = tid & 63, wid = tid >> 6;
  const int wm = wid >> 2, wn = wid & 3;
  const int fr = lane & 15, fq = lane >> 4;
  const int sw0 = fq ^ (fr & 7);        // k-step 0: chunk (0*4+fq) ^ (row&7)
  const int sw1 = (4 + fq) ^ (fr & 7);  // k-step 1
  const __bf16* Ab = A + (size_t)((EPI == 0) ? by : b) * 65536;
  const __bf16* Bb = Bx + ((size_t)b * NPIX + (size_t)bx * 256) * 256;

  fx4 acc[8][4] = {};
  bh8 a[4][2], b0[2][2], b1[2][2];

  // ---- prologue: tile0 {Blo,Alo,Ahi,Bhi} -> buf0, tile1 {Blo,Alo} -> buf1
  STG(0, 2, 0); STG(0, 0, 0); STG(0, 1, 0); STG(0, 3, 0);
  STG(1, 2, 1); STG(1, 0, 1);
  VMW4();  // 12 issued, oldest 8 (tile0) retired
  pbar();

  // ---- iteration 1: compute tiles 0 (buf0) and 1 (buf1); stage tiles 2,3
  LDA(0, 0); LDB(0, 0, b0); STG(1, 1, 1); pbar(); MMA(0, 0, b0); pbar();  // P1
  LDB(0, 1, b1);            STG(1, 3, 1); pbar(); MMA(0, 1, b1); pbar();  // P2
  LDA(0, 1);                STG(0, 2, 2); pbar(); MMA(1, 1, b1); pbar();  // P3
                            STG(0, 0, 2); pbar(); MMA(1, 0, b0); VMW4(); pbar();  // P4
  LDA(1, 0); LDB(1, 0, b0); STG(0, 1, 2); pbar(); MMA(0, 0, b0); pbar();  // P5
  LDB(1, 1, b1);            STG(0, 3, 2); pbar(); MMA(0, 1, b1); pbar();  // P6
  LDA(1, 1);                STG(1, 2, 3); pbar(); MMA(1, 1, b1); pbar();  // P7
                            STG(1, 0, 3); pbar(); MMA(1, 0, b0); VMW4(); pbar();  // P8

  // ---- iteration 2: compute tiles 2 (buf0) and 3 (buf1); finish tile3 stage
  LDA(0, 0); LDB(0, 0, b0); STG(1, 1, 3); pbar(); MMA(0, 0, b0); pbar();  // P1
  LDB(0, 1, b1);            STG(1, 3, 3); pbar(); MMA(0, 1, b1); pbar();  // P2
  LDA(0, 1);                              pbar(); MMA(1, 1, b1); pbar();  // P3
                                          pbar(); MMA(1, 0, b0); VMW0(); pbar();  // P4
  LDA(1, 0); LDB(1, 0, b0);               pbar(); MMA(0, 0, b0); pbar();  // P5
  LDB(1, 1, b1);                          pbar(); MMA(0, 1, b1); pbar();  // P6
  LDA(1, 1);                              pbar(); MMA(1, 1, b1); pbar();  // P7
                                          pbar(); MMA(1, 0, b0); pbar();  // P8

  // ---- epilogue
#pragma unroll
  for (int m = 0; m < 8; ++m) {
#pragma unroll
    for (int n = 0; n < 4; ++n) {
      const int o = wm * 128 + m * 16 + fq * 4;          // output row (channel)
      const int px = bx * 256 + wn * 64 + n * 16 + fr;   // pixel
      if (EPI == 0) {
        if (by == 0) {  // q -> qT [b][n][256] bf16
          bh4 v4;
#pragma unroll
          for (int j = 0; j < 4; ++j) v4[j] = (__bf16)acc[m][n][j];
          *(bh4*)&qT[((size_t)b * NPIX + px) * CDIM + o] = v4;
        } else if (by == 1) {  // k -> exp(k), row-major [b][256][NPIX]
#pragma unroll
          for (int j = 0; j < 4; ++j)
            ekmat[((size_t)b * CDIM + o + j) * NPIX + px] = (__bf16)__expf(acc[m][n][j]);
        } else {  // v row-major
#pragma unroll
          for (int j = 0; j < 4; ++j)
            vmat[((size_t)b * CDIM + o + j) * NPIX + px] = (__bf16)acc[m][n][j];
        }
      } else {
#pragma unroll
        for (int j = 0; j < 4; ++j)
          fout[((size_t)b * CDIM + o + j) * NPIX + px] = acc[m][n][j] + bias[o + j];
      }
    }
  }
}

// ---------------- pass 2: S[d][e] = sum_n ek[d,n] v[e,n]; Z[d]=sum_n ek ------
__global__ __launch_bounds__(256) void ctx_kernel(const __bf16* __restrict__ ekmat,
                                                  const __bf16* __restrict__ vmat,
                                                  float* __restrict__ S_part,
                                                  float* __restrict__ Zsum) {
  const int chunk = blockIdx.x, h = blockIdx.y, b = blockIdx.z;
  const int t = threadIdx.x;
  const int n0 = chunk * 256;
  __shared__ __bf16 EK[32 * 256];
  __shared__ __bf16 VS[32 * 256];
  __shared__ float zrow[32];

  if (t < 32) zrow[t] = 0.f;
  // stage exp(k) and v via global_load_lds (both pre-computed bf16 row-major)
#pragma unroll
  for (int i = 0; i < 4; ++i) {
    int e0 = i * 2048 + t * 8;
    int row = e0 >> 8, col = e0 & 255;
    gload16(ekmat + ((size_t)b * CDIM + h * 32 + row) * NPIX + n0 + col, (void*)(EK + e0));
    gload16(vmat  + ((size_t)b * CDIM + h * 32 + row) * NPIX + n0 + col, (void*)(VS + e0));
  }
  __syncthreads();  // drains vmcnt(0) -> stages landed, zrow zeros visible

  {  // Z partial: thread t sums 32 values of row t>>3
    const int row = t >> 3, c0 = (t & 7) * 32;
    float zacc = 0.f;
#pragma unroll
    for (int i = 0; i < 4; ++i) {
      bh8 ev = *(const bh8*)&EK[row * 256 + c0 + i * 8];
#pragma unroll
      for (int j = 0; j < 8; ++j) zacc += (float)ev[j];
    }
    atomicAdd(&zrow[row], zacc);
  }

  const int wid = t >> 6, lane = t & 63, fr = lane & 15, fq = lane >> 4;
  fx4 acc[2][2] = {};
  const int kbase = wid * 64;  // each wave: 64 of the 256 K
#pragma unroll
  for (int kk = 0; kk < 2; ++kk) {
    bh8 a[2], bb[2];
#pragma unroll
    for (int m = 0; m < 2; ++m)
      a[m] = *(const bh8*)&EK[(m * 16 + fr) * 256 + kbase + kk * 32 + fq * 8];
#pragma unroll
    for (int n = 0; n < 2; ++n)
      bb[n] = *(const bh8*)&VS[(n * 16 + fr) * 256 + kbase + kk * 32 + fq * 8];
#pragma unroll
    for (int m = 0; m < 2; ++m)
#pragma unroll
      for (int n = 0; n < 2; ++n) acc[m][n] = mfma16(a[m], bb[n], acc[m][n]);
  }
  __syncthreads();
  float* red = (float*)EK;  // 4096 f32 scratch over EK (16 KB)
#pragma unroll
  for (int m = 0; m < 2; ++m)
#pragma unroll
    for (int n = 0; n < 2; ++n)
#pragma unroll
      for (int j = 0; j < 4; ++j)
        red[wid * 1024 + (m * 16 + fq * 4 + j) * 32 + (n * 16 + fr)] = acc[m][n][j];
  __syncthreads();
  const size_t bh = (size_t)b * 8 + h;
  for (int i = t; i < 1024; i += 256) {
    float s = red[i] + red[1024 + i] + red[2048 + i] + red[3072 + i];
    S_part[(bh * 64 + chunk) * 1024 + i] = s;
  }
  if (t < 32) atomicAdd(&Zsum[bh * 32 + t], zrow[t]);
}

// ---------------- pass 2.5: reduce S_part over chunks, divide by Z -> ctx ----
__global__ __launch_bounds__(256) void reduce_ctx(const float* __restrict__ S_part,
                                                  const float* __restrict__ Zsum,
                                                  float* __restrict__ ctx) {
  const int bh = blockIdx.x;  // 64
  const int t = threadIdx.x;
  for (int i = t; i < 1024; i += 256) {
    float s = 0.f;
    for (int ch = 0; ch < 64; ++ch) s += S_part[((size_t)bh * 64 + ch) * 1024 + i];
    ctx[(size_t)bh * 1024 + i] = s / Zsum[bh * 32 + (i >> 5)];
  }
}

// ---------------- pass 3: W2[b][oc][h*32+d] = sum_e w_out[oc][h*32+e]*ctx ----
__global__ __launch_bounds__(256) void make_w2(const float* __restrict__ ctx,
                                               const float* __restrict__ w_out,
                                               __bf16* __restrict__ W2) {
  const int oc = blockIdx.x, b = blockIdx.y, t = threadIdx.x;
  const int h = t >> 5, d = t & 31;
  const float* wrow = w_out + oc * 256 + h * 32;
  const float* crow = ctx + (((size_t)b * 8 + h) * 32 + d) * 32;
  float s = 0.f;
#pragma unroll
  for (int e = 0; e < 32; ++e) s += wrow[e] * crow[e];
  W2[((size_t)b * 256 + oc) * 256 + t] = (__bf16)s;
}

extern "C" void kernel_launch(void* const* d_in, const int* in_sizes, int n_in,
                              void* d_out, int out_size, void* d_ws, size_t ws_size,
                              hipStream_t stream) {
  const float* x     = (const float*)d_in[0];
  const float* w_qkv = (const float*)d_in[1];
  const float* w_out = (const float*)d_in[2];
  const float* b_out = (const float*)d_in[3];
  float* out = (float*)d_out;

  char* ws = (char*)d_ws;
  __bf16* xT    = (__bf16*)(ws);                          // 67,108,864
  __bf16* qT    = (__bf16*)(ws + 67108864ull);            // 67,108,864
  __bf16* wqb   = (__bf16*)(ws + 134217728ull);           // 393,216
  __bf16* W2    = (__bf16*)(ws + 134610944ull);           // 1,048,576
  float*  S_part= (float*) (ws + 135659520ull);           // 16,777,216
  float*  Zsum  = (float*) (ws + 152436736ull);           // 8,192
  float*  ctx   = (float*) (ws + 152444928ull);           // 262,144

  // exp(k)/v bf16 scratch lives inside d_out (fully overwritten by gemm_out)
  __bf16* ekmat = (__bf16*)d_out;                      // [8][256][NPIX] 64 MiB
  __bf16* vmat  = ekmat + (size_t)BATCH * CDIM * NPIX; // next 64 MiB

  hipMemsetAsync(Zsum, 0, 8192, stream);

  conv_w<<<768, 256, 0, stream>>>(w_qkv, wqb, MQKV * CDIM);
  transpose_x<<<dim3(NPIX / 32, CDIM / 32, BATCH), 256, 0, stream>>>(x, xT);
  gemm256<0><<<dim3(NPIX / 256, 3, BATCH), 512, 0, stream>>>(
      wqb, xT, qT, ekmat, vmat, nullptr, nullptr);
  ctx_kernel<<<dim3(64, 8, BATCH), 256, 0, stream>>>(ekmat, vmat, S_part, Zsum);
  reduce_ctx<<<64, 256, 0, stream>>>(S_part, Zsum, ctx);
  make_w2<<<dim3(256, BATCH), 256, 0, stream>>>(ctx, w_out, W2);
  gemm256<1><<<dim3(NPIX / 256, 1, BATCH), 512, 0, stream>>>(
      W2, qT, nullptr, nullptr, nullptr, b_out, out);
}

// Round 3
// 227.102 us; speedup vs baseline: 1.0218x; 1.0212x over previous
//
#include <hip/hip_runtime.h>
#include <hip/hip_bf16.h>
#include <cstdint>

#define NPIX 16384   // h*w = 128*128
#define BATCH 8
#define CDIM 256
#define MQKV 768

typedef __bf16 bh8 __attribute__((ext_vector_type(8)));
typedef __bf16 bh4 __attribute__((ext_vector_type(4)));
typedef float  fx4 __attribute__((ext_vector_type(4)));

__device__ __forceinline__ void gload16(const void* g, void* l) {
  __builtin_amdgcn_global_load_lds(
      (const __attribute__((address_space(1))) uint32_t*)g,
      (__attribute__((address_space(3))) uint32_t*)l, 16, 0, 0);
}

__device__ __forceinline__ fx4 mfma16(bh8 a, bh8 b, fx4 c) {
  return __builtin_amdgcn_mfma_f32_16x16x32_bf16(a, b, c, 0, 0, 0);
}

__device__ __forceinline__ void pbar() {
  asm volatile("" ::: "memory");
  __builtin_amdgcn_s_barrier();
  asm volatile("" ::: "memory");
}
#define VMWI(n) asm volatile("s_waitcnt vmcnt(" #n ")" ::: "memory")

// ---------------- pass 0a: convert w_qkv f32 -> bf16 (row-major [768][256]) --
__global__ void conv_w(const float* __restrict__ w, __bf16* __restrict__ wb, int n) {
  int i = blockIdx.x * 256 + threadIdx.x;
  if (i < n) wb[i] = (__bf16)w[i];
}

// ---------------- pass 0b: x [b][256][NPIX] f32 -> xT [b][NPIX][256] bf16 ----
__global__ __launch_bounds__(256) void transpose_x(const float* __restrict__ x,
                                                   __bf16* __restrict__ xT) {
  __shared__ float tile[32][33];
  const int n0 = blockIdx.x * 32, c0 = blockIdx.y * 32, b = blockIdx.z;
  const int tx = threadIdx.x & 31, ty = threadIdx.x >> 5;
#pragma unroll
  for (int j = 0; j < 4; ++j) {
    int r = ty * 4 + j;  // local c
    tile[r][tx] = x[((size_t)b * CDIM + c0 + r) * NPIX + n0 + tx];
  }
  __syncthreads();
#pragma unroll
  for (int j = 0; j < 4; ++j) {
    int nl = ty * 4 + j; // local n
    xT[((size_t)b * NPIX + n0 + nl) * CDIM + c0 + tx] = (__bf16)tile[tx][nl];
  }
}

// ====== 256x128 tile GEMM, K=256 as 4 x BK=64, 512 thr, 2 blocks/CU =========
// A single-buffered (32KB), B double-buffered (2x16KB). All staging via
// global_load_lds with r2's conflict-free chunk-XOR swizzle (128B rows,
// 16B chunk c of row r stored at c ^ (r&7); source pre-swizzled).
// Waves: wid 0..7 -> wm=wid>>1 (4 x 64 rows), wn=wid&1 (2 x 64 cols).
// Counted vmcnt(2): next B-tile (2 loads) stays in flight across barriers.

#define STA(kt)                                                                \
  do {                                                                         \
    _Pragma("unroll") for (int i_ = 0; i_ < 4; ++i_) {                         \
      int j_ = i_ * 512 + tid;                                                 \
      int row_ = j_ >> 3, c_ = j_ & 7;                                         \
      int sc_ = c_ ^ (row_ & 7);                                               \
      gload16(Ab + (size_t)row_ * 256 + (kt)*64 + sc_ * 8, As + j_ * 8);       \
    }                                                                          \
  } while (0)

#define STB(kt, pb)                                                            \
  do {                                                                         \
    _Pragma("unroll") for (int i_ = 0; i_ < 2; ++i_) {                         \
      int j_ = i_ * 512 + tid;                                                 \
      int row_ = j_ >> 3, c_ = j_ & 7;                                         \
      int sc_ = c_ ^ (row_ & 7);                                               \
      gload16(Bb + (size_t)row_ * 256 + (kt)*64 + sc_ * 8, &Bs[pb][j_ * 8]);   \
    }                                                                          \
  } while (0)

#define COMP(pb)                                                               \
  do {                                                                         \
    _Pragma("unroll") for (int ks_ = 0; ks_ < 2; ++ks_) {                      \
      bh8 a_[4], b_[4];                                                        \
      const int swk_ = (ks_ * 4 + fq) ^ (fr & 7);                              \
      _Pragma("unroll") for (int m_ = 0; m_ < 4; ++m_)                         \
        a_[m_] = *(const bh8*)&As[(wm * 64 + m_ * 16 + fr) * 64 + swk_ * 8];   \
      _Pragma("unroll") for (int n_ = 0; n_ < 4; ++n_)                         \
        b_[n_] = *(const bh8*)&Bs[pb][(wn * 64 + n_ * 16 + fr) * 64 + swk_ * 8];\
      _Pragma("unroll") for (int m_ = 0; m_ < 4; ++m_)                         \
      _Pragma("unroll") for (int n_ = 0; n_ < 4; ++n_)                         \
        acc[m_][n_] = mfma16(a_[m_], b_[n_], acc[m_][n_]);                     \
    }                                                                          \
  } while (0)

template <int EPI>
__global__ __launch_bounds__(512, 4) void gemm256(
    const __bf16* __restrict__ A, const __bf16* __restrict__ Bx,
    __bf16* __restrict__ qT, __bf16* __restrict__ ekmat,
    __bf16* __restrict__ vmat, const float* __restrict__ bias,
    float* __restrict__ fout) {
  __shared__ __bf16 As[16384];      // [256 rows][64k]
  __shared__ __bf16 Bs[2][8192];    // [128 rows][64k] x2
  const int tid = threadIdx.x;
  const int bx = blockIdx.x, by = blockIdx.y, b = blockIdx.z;
  const int lane = tid & 63, wid = tid >> 6;
  const int wm = wid >> 1, wn = wid & 1;
  const int fr = lane & 15, fq = lane >> 4;
  const __bf16* Ab = A + (size_t)((EPI == 0) ? by : b) * 65536;
  const __bf16* Bb = Bx + ((size_t)b * NPIX + (size_t)bx * 128) * 256;

  fx4 acc[4][4] = {};

  STB(0, 0); STA(0);
  STB(1, 1); VMWI(2); pbar(); COMP(0); pbar(); STA(1);
  STB(2, 0); VMWI(2); pbar(); COMP(1); pbar(); STA(2);
  STB(3, 1); VMWI(2); pbar(); COMP(0); pbar(); STA(3);
             VMWI(0); pbar(); COMP(1); pbar();

  // ---- epilogue
#pragma unroll
  for (int m = 0; m < 4; ++m) {
#pragma unroll
    for (int n = 0; n < 4; ++n) {
      const int o = wm * 64 + m * 16 + fq * 4;           // channel 0..255
      const int px = bx * 128 + wn * 64 + n * 16 + fr;   // pixel
      if (EPI == 0) {
        if (by == 0) {  // q -> qT [b][n][256] bf16
          bh4 v4;
#pragma unroll
          for (int j = 0; j < 4; ++j) v4[j] = (__bf16)acc[m][n][j];
          *(bh4*)&qT[((size_t)b * NPIX + px) * CDIM + o] = v4;
        } else if (by == 1) {  // k -> exp(k), row-major [b][256][NPIX]
#pragma unroll
          for (int j = 0; j < 4; ++j)
            ekmat[((size_t)b * CDIM + o + j) * NPIX + px] = (__bf16)__expf(acc[m][n][j]);
        } else {  // v row-major
#pragma unroll
          for (int j = 0; j < 4; ++j)
            vmat[((size_t)b * CDIM + o + j) * NPIX + px] = (__bf16)acc[m][n][j];
        }
      } else {
#pragma unroll
        for (int j = 0; j < 4; ++j)
          fout[((size_t)b * CDIM + o + j) * NPIX + px] = acc[m][n][j] + bias[o + j];
      }
    }
  }
}

// ---------------- pass 2: S[d][e] = sum_n ek[d,n] v[e,n]; Z[d]=sum_n ek ------
__global__ __launch_bounds__(256) void ctx_kernel(const __bf16* __restrict__ ekmat,
                                                  const __bf16* __restrict__ vmat,
                                                  float* __restrict__ S_part,
                                                  float* __restrict__ Zsum) {
  const int chunk = blockIdx.x, h = blockIdx.y, b = blockIdx.z;
  const int t = threadIdx.x;
  const int n0 = chunk * 256;
  __shared__ __bf16 EK[32 * 256];
  __shared__ __bf16 VS[32 * 256];
  __shared__ float zrow[32];

  if (t < 32) zrow[t] = 0.f;
#pragma unroll
  for (int i = 0; i < 4; ++i) {
    int e0 = i * 2048 + t * 8;
    int row = e0 >> 8, col = e0 & 255;
    gload16(ekmat + ((size_t)b * CDIM + h * 32 + row) * NPIX + n0 + col, (void*)(EK + e0));
    gload16(vmat  + ((size_t)b * CDIM + h * 32 + row) * NPIX + n0 + col, (void*)(VS + e0));
  }
  __syncthreads();

  {  // Z partial: thread t sums 32 values of row t>>3
    const int row = t >> 3, c0 = (t & 7) * 32;
    float zacc = 0.f;
#pragma unroll
    for (int i = 0; i < 4; ++i) {
      bh8 ev = *(const bh8*)&EK[row * 256 + c0 + i * 8];
#pragma unroll
      for (int j = 0; j < 8; ++j) zacc += (float)ev[j];
    }
    atomicAdd(&zrow[row], zacc);
  }

  const int wid = t >> 6, lane = t & 63, fr = lane & 15, fq = lane >> 4;
  fx4 acc[2][2] = {};
  const int kbase = wid * 64;
#pragma unroll
  for (int kk = 0; kk < 2; ++kk) {
    bh8 a[2], bb[2];
#pragma unroll
    for (int m = 0; m < 2; ++m)
      a[m] = *(const bh8*)&EK[(m * 16 + fr) * 256 + kbase + kk * 32 + fq * 8];
#pragma unroll
    for (int n = 0; n < 2; ++n)
      bb[n] = *(const bh8*)&VS[(n * 16 + fr) * 256 + kbase + kk * 32 + fq * 8];
#pragma unroll
    for (int m = 0; m < 2; ++m)
#pragma unroll
      for (int n = 0; n < 2; ++n) acc[m][n] = mfma16(a[m], bb[n], acc[m][n]);
  }
  __syncthreads();
  float* red = (float*)EK;
#pragma unroll
  for (int m = 0; m < 2; ++m)
#pragma unroll
    for (int n = 0; n < 2; ++n)
#pragma unroll
      for (int j = 0; j < 4; ++j)
        red[wid * 1024 + (m * 16 + fq * 4 + j) * 32 + (n * 16 + fr)] = acc[m][n][j];
  __syncthreads();
  const size_t bh = (size_t)b * 8 + h;
  for (int i = t; i < 1024; i += 256) {
    float s = red[i] + red[1024 + i] + red[2048 + i] + red[3072 + i];
    S_part[(bh * 64 + chunk) * 1024 + i] = s;
  }
  if (t < 32) atomicAdd(&Zsum[bh * 32 + t], zrow[t]);
}

// ---------------- pass 2.5: reduce S_part over chunks, divide by Z -> ctx ----
__global__ __launch_bounds__(256) void reduce_ctx(const float* __restrict__ S_part,
                                                  const float* __restrict__ Zsum,
                                                  float* __restrict__ ctx) {
  const int bh = blockIdx.x;
  const int t = threadIdx.x;
  for (int i = t; i < 1024; i += 256) {
    float s = 0.f;
    for (int ch = 0; ch < 64; ++ch) s += S_part[((size_t)bh * 64 + ch) * 1024 + i];
    ctx[(size_t)bh * 1024 + i] = s / Zsum[bh * 32 + (i >> 5)];
  }
}

// ---------------- pass 3: W2[b][oc][h*32+d] = sum_e w_out[oc][h*32+e]*ctx ----
__global__ __launch_bounds__(256) void make_w2(const float* __restrict__ ctx,
                                               const float* __restrict__ w_out,
                                               __bf16* __restrict__ W2) {
  const int oc = blockIdx.x, b = blockIdx.y, t = threadIdx.x;
  const int h = t >> 5, d = t & 31;
  const float* wrow = w_out + oc * 256 + h * 32;
  const float* crow = ctx + (((size_t)b * 8 + h) * 32 + d) * 32;
  float s = 0.f;
#pragma unroll
  for (int e = 0; e < 32; ++e) s += wrow[e] * crow[e];
  W2[((size_t)b * 256 + oc) * 256 + t] = (__bf16)s;
}

extern "C" void kernel_launch(void* const* d_in, const int* in_sizes, int n_in,
                              void* d_out, int out_size, void* d_ws, size_t ws_size,
                              hipStream_t stream) {
  const float* x     = (const float*)d_in[0];
  const float* w_qkv = (const float*)d_in[1];
  const float* w_out = (const float*)d_in[2];
  const float* b_out = (const float*)d_in[3];
  float* out = (float*)d_out;

  char* ws = (char*)d_ws;
  __bf16* xT    = (__bf16*)(ws);                          // 67,108,864
  __bf16* qT    = (__bf16*)(ws + 67108864ull);            // 67,108,864
  __bf16* wqb   = (__bf16*)(ws + 134217728ull);           // 393,216
  __bf16* W2    = (__bf16*)(ws + 134610944ull);           // 1,048,576
  float*  S_part= (float*) (ws + 135659520ull);           // 16,777,216
  float*  Zsum  = (float*) (ws + 152436736ull);           // 8,192
  float*  ctx   = (float*) (ws + 152444928ull);           // 262,144

  __bf16* ekmat = (__bf16*)d_out;                      // [8][256][NPIX] 64 MiB
  __bf16* vmat  = ekmat + (size_t)BATCH * CDIM * NPIX; // next 64 MiB

  hipMemsetAsync(Zsum, 0, 8192, stream);

  conv_w<<<768, 256, 0, stream>>>(w_qkv, wqb, MQKV * CDIM);
  transpose_x<<<dim3(NPIX / 32, CDIM / 32, BATCH), 256, 0, stream>>>(x, xT);
  gemm256<0><<<dim3(NPIX / 128, 3, BATCH), 512, 0, stream>>>(
      wqb, xT, qT, ekmat, vmat, nullptr, nullptr);
  ctx_kernel<<<dim3(64, 8, BATCH), 256, 0, stream>>>(ekmat, vmat, S_part, Zsum);
  reduce_ctx<<<64, 256, 0, stream>>>(S_part, Zsum, ctx);
  make_w2<<<dim3(256, BATCH), 256, 0, stream>>>(ctx, w_out, W2);
  gemm256<1><<<dim3(NPIX / 128, 1, BATCH), 512, 0, stream>>>(
      W2, qT, nullptr, nullptr, nullptr, b_out, out);
}